// Round 1
// 291.966 us; speedup vs baseline: 1.0196x; 1.0196x over previous
//
#include <hip/hip_runtime.h>

#define NN 50000
#define EE 800000
#define DD 128
#define CAP 48     // bucket capacity; graph degrees ~Poisson(16), P(>=48)~6e-11
#define MT 64      // nodes per gemm block
#define XSL 6250   // nodes per XCD slice (NN/8)
#define PB 128     // place blocks per XCD

typedef short short8_t __attribute__((ext_vector_type(8)));
typedef float f32x4 __attribute__((ext_vector_type(4)));

// f32 -> bf16 (round-to-nearest-even)
__device__ __forceinline__ unsigned short f2bf(float f) {
    union { float f; unsigned int i; } v; v.f = f;
    unsigned int x = v.i;
    x += 0x7FFFu + ((x >> 16) & 1u);
    return (unsigned short)(x >> 16);
}
__device__ __forceinline__ unsigned int pack2(float a, float b) {
    return (unsigned int)f2bf(a) | ((unsigned int)f2bf(b) << 16);
}
// packed bf16 pair -> two f32 (elem0 = low half)
__device__ __forceinline__ float2 bf2x2(unsigned int u) {
    union { unsigned int i; float f; } lo, hi;
    lo.i = u << 16;
    hi.i = u & 0xFFFF0000u;
    return make_float2(lo.f, hi.f);
}

// Fused bf16 conversion: x (NN*DD floats) then the 3 weight mats (W_fc pre-scaled 0.5).
__global__ void k_conv(const float* __restrict__ x,
                       const float* __restrict__ W_src,
                       const float* __restrict__ W_dst,
                       const float* __restrict__ W_fc,
                       unsigned short* __restrict__ xb,
                       unsigned short* __restrict__ wbf) {
    int t = blockIdx.x * 256 + threadIdx.x;
    int base = t * 4;
    if (base < NN * DD) {
        float4 v = *(const float4*)(x + base);
        uint2 p; p.x = pack2(v.x, v.y); p.y = pack2(v.z, v.w);
        *(uint2*)(xb + base) = p;
    } else {
        int b2 = base - NN * DD;
        if (b2 < 3 * 16384) {
            int src = b2 >> 14;
            int off = b2 & 16383;
            const float* W = (src == 0) ? W_src : (src == 1) ? W_dst : W_fc;
            float sc = (src == 2) ? 0.5f : 1.0f;
            float4 v = *(const float4*)(W + off);
            uint2 p; p.x = pack2(v.x * sc, v.y * sc); p.y = pack2(v.z * sc, v.w * sc);
            *(uint2*)(wbf + b2) = p;
        }
    }
}

// XCD-sliced bucket fill: block's XCD (empirically blockIdx&7) owns node slice
// [xcd*XSL, (xcd+1)*XSL); each XCD scans all edges, writes only its slice ->
// every bucket cache line is written by ~one XCD (kills writeback amplification).
// Correctness does NOT depend on the XCD mapping (any block may write any slice).
__global__ void __launch_bounds__(256) k_place(
    const int* __restrict__ ei, int* __restrict__ cnt,
    unsigned short* __restrict__ bkt_row, unsigned short* __restrict__ bkt_col) {
    int xcd = blockIdx.x & 7;
    int b   = blockIdx.x >> 3;
    int lo = xcd * XSL, hi = lo + XSL;
    for (int e = b * 256 + threadIdx.x; e < EE; e += PB * 256) {
        int r = ei[e];
        int c = ei[EE + e];
        if (r >= lo && r < hi) {
            int po = atomicAdd(&cnt[r], 1);
            if (po < CAP) bkt_row[(size_t)r * CAP + po] = (unsigned short)c;
        }
        if (c >= lo && c < hi) {
            int pi = atomicAdd(&cnt[NN + c], 1);
            if (pi < CAP) bkt_col[(size_t)c * CAP + pi] = (unsigned short)r;
        }
    }
}

__global__ void k_inv(const int* __restrict__ cnt, float* __restrict__ inv) {
    int t = blockIdx.x * 256 + threadIdx.x;
    if (t >= 2 * NN) return;
    int d = cnt[t];
    inv[t] = (d > 0) ? (1.0f / sqrtf((float)d)) : 0.0f;
}

// Bucket gather (bf16 x) + fused gate. 2 nodes/block; per node 128 threads:
// groups 0-1 gather the OUT direction, groups 2-3 gather the IN direction
// CONCURRENTLY (2x memory-level parallelism vs serialized phases). Each group
// owns neighbors j = gd, gd+2, ... with an 8-deep unrolled tier so a typical
// degree-16 row set is fully in flight. onb/inb are written PRE-SCALED by
// Cout/Cin so the GEMM A-staging is a pure copy.
__global__ void __launch_bounds__(256) k_gather(
    const uint2* __restrict__ xb2, const float4* __restrict__ x4,
    const unsigned short* __restrict__ bkt_row, const unsigned short* __restrict__ bkt_col,
    const int* __restrict__ cnt,
    const float* __restrict__ o_inv, const float* __restrict__ i_inv,
    const int* __restrict__ in_degree, const int* __restrict__ out_degree,
    const float* __restrict__ odm, const float* __restrict__ odmb,
    const float* __restrict__ idm, const float* __restrict__ idmb,
    const float4* __restrict__ W_out_f4, const float* __restrict__ b_out_f,
    const float4* __restrict__ W_in_f4, const float* __restrict__ b_in_f,
    const float4* __restrict__ in_tab4, const float4* __restrict__ out_tab4,
    uint2* __restrict__ onb2, uint2* __restrict__ inb2,
    float* __restrict__ scbuf,
    float* __restrict__ outCin, float* __restrict__ outCout)
{
    __shared__ float4 sred[2][4][32];
    __shared__ float sg[2][2];
    __shared__ float sC[2][2];
    int half = threadIdx.x >> 7;
    int n = blockIdx.x * 2 + half;
    int t = threadIdx.x & 127;
    int g = t >> 5;       // 0,1 -> out direction; 2,3 -> in direction
    int l = t & 31;
    int dir = g >> 1;     // 0 = out, 1 = in
    int gd  = g & 1;      // group index within direction

    const unsigned short* bp = ((dir == 0) ? bkt_row : bkt_col) + (size_t)n * CAP;
    const float* wnb = (dir == 0) ? i_inv : o_inv;   // neighbor weight table
    int deg = cnt[dir * NN + n]; deg = (deg > CAP) ? CAP : deg;

    float4 acc = make_float4(0.f, 0.f, 0.f, 0.f);
    int j = gd;
    for (; j + 14 < deg; j += 16) {
        int nb0 = bp[j],      nb1 = bp[j + 2],  nb2_ = bp[j + 4],  nb3 = bp[j + 6];
        int nb4 = bp[j + 8],  nb5 = bp[j + 10], nb6 = bp[j + 12],  nb7 = bp[j + 14];
        float w0 = wnb[nb0], w1 = wnb[nb1], w2 = wnb[nb2_], w3 = wnb[nb3];
        float w4 = wnb[nb4], w5 = wnb[nb5], w6 = wnb[nb6],  w7 = wnb[nb7];
        uint2 u0 = xb2[(size_t)nb0 * 32 + l];
        uint2 u1 = xb2[(size_t)nb1 * 32 + l];
        uint2 u2 = xb2[(size_t)nb2_ * 32 + l];
        uint2 u3 = xb2[(size_t)nb3 * 32 + l];
        uint2 u4 = xb2[(size_t)nb4 * 32 + l];
        uint2 u5 = xb2[(size_t)nb5 * 32 + l];
        uint2 u6 = xb2[(size_t)nb6 * 32 + l];
        uint2 u7 = xb2[(size_t)nb7 * 32 + l];
        float2 p0 = bf2x2(u0.x), p1 = bf2x2(u0.y);
        float2 q0 = bf2x2(u1.x), q1 = bf2x2(u1.y);
        float2 r0 = bf2x2(u2.x), r1 = bf2x2(u2.y);
        float2 s0 = bf2x2(u3.x), s1 = bf2x2(u3.y);
        float2 t0 = bf2x2(u4.x), t1 = bf2x2(u4.y);
        float2 v0 = bf2x2(u5.x), v1 = bf2x2(u5.y);
        float2 y0 = bf2x2(u6.x), y1 = bf2x2(u6.y);
        float2 z0 = bf2x2(u7.x), z1 = bf2x2(u7.y);
        acc.x += w0 * p0.x + w1 * q0.x + w2 * r0.x + w3 * s0.x
               + w4 * t0.x + w5 * v0.x + w6 * y0.x + w7 * z0.x;
        acc.y += w0 * p0.y + w1 * q0.y + w2 * r0.y + w3 * s0.y
               + w4 * t0.y + w5 * v0.y + w6 * y0.y + w7 * z0.y;
        acc.z += w0 * p1.x + w1 * q1.x + w2 * r1.x + w3 * s1.x
               + w4 * t1.x + w5 * v1.x + w6 * y1.x + w7 * z1.x;
        acc.w += w0 * p1.y + w1 * q1.y + w2 * r1.y + w3 * s1.y
               + w4 * t1.y + w5 * v1.y + w6 * y1.y + w7 * z1.y;
    }
    for (; j + 6 < deg; j += 8) {
        int nb0 = bp[j], nb1 = bp[j + 2], nb2_ = bp[j + 4], nb3 = bp[j + 6];
        float w0 = wnb[nb0], w1 = wnb[nb1], w2 = wnb[nb2_], w3 = wnb[nb3];
        uint2 u0 = xb2[(size_t)nb0 * 32 + l];
        uint2 u1 = xb2[(size_t)nb1 * 32 + l];
        uint2 u2 = xb2[(size_t)nb2_ * 32 + l];
        uint2 u3 = xb2[(size_t)nb3 * 32 + l];
        float2 p0 = bf2x2(u0.x), p1 = bf2x2(u0.y);
        float2 q0 = bf2x2(u1.x), q1 = bf2x2(u1.y);
        float2 r0 = bf2x2(u2.x), r1 = bf2x2(u2.y);
        float2 s0 = bf2x2(u3.x), s1 = bf2x2(u3.y);
        acc.x += w0 * p0.x + w1 * q0.x + w2 * r0.x + w3 * s0.x;
        acc.y += w0 * p0.y + w1 * q0.y + w2 * r0.y + w3 * s0.y;
        acc.z += w0 * p1.x + w1 * q1.x + w2 * r1.x + w3 * s1.x;
        acc.w += w0 * p1.y + w1 * q1.y + w2 * r1.y + w3 * s1.y;
    }
    for (; j + 2 < deg; j += 4) {
        int nb0 = bp[j], nb1 = bp[j + 2];
        float w0 = wnb[nb0], w1 = wnb[nb1];
        uint2 u0 = xb2[(size_t)nb0 * 32 + l];
        uint2 u1 = xb2[(size_t)nb1 * 32 + l];
        float2 p0 = bf2x2(u0.x), p1 = bf2x2(u0.y);
        float2 q0 = bf2x2(u1.x), q1 = bf2x2(u1.y);
        acc.x += w0 * p0.x + w1 * q0.x;
        acc.y += w0 * p0.y + w1 * q0.y;
        acc.z += w0 * p1.x + w1 * q1.x;
        acc.w += w0 * p1.y + w1 * q1.y;
    }
    if (j < deg) {
        int nb = bp[j];
        float w = wnb[nb];
        uint2 u = xb2[(size_t)nb * 32 + l];
        float2 p0 = bf2x2(u.x), p1 = bf2x2(u.y);
        acc.x += w * p0.x; acc.y += w * p0.y; acc.z += w * p1.x; acc.w += w * p1.y;
    }

    sred[half][g][l] = acc;
    __syncthreads();

    float4 r = make_float4(0.f, 0.f, 0.f, 0.f);
    if (gd == 0) {
        float4 a0 = sred[half][dir * 2][l];
        float4 a1 = sred[half][dir * 2 + 1][l];
        float wn = (dir == 0) ? o_inv[n] : i_inv[n];
        r.x = wn * (a0.x + a1.x);
        r.y = wn * (a0.y + a1.y);
        r.z = wn * (a0.z + a1.z);
        r.w = wn * (a0.w + a1.w);
        float4 xv = x4[(size_t)n * 32 + l];
        float4 tb, wf;
        if (dir == 0) {
            int odg = out_degree[n];
            odg = (odg < 0) ? 0 : (odg > 63 ? 63 : odg);
            tb = out_tab4[(size_t)odg * 32 + l];
            wf = W_out_f4[l];
        } else {
            int idg = in_degree[n];
            idg = (idg < 0) ? 0 : (idg > 63 ? 63 : idg);
            tb = in_tab4[(size_t)idg * 32 + l];
            wf = W_in_f4[l];
        }
        float p = (r.x - xv.x + tb.x) * wf.x + (r.y - xv.y + tb.y) * wf.y
                + (r.z - xv.z + tb.z) * wf.z + (r.w - xv.w + tb.w) * wf.w;
        #pragma unroll
        for (int off = 16; off > 0; off >>= 1) p += __shfl_down(p, off);
        if (l == 0) sg[half][dir] = p;
    }
    __syncthreads();
    if (t == 0) {
        float c_out = sg[half][0] + b_out_f[0];
        float c_in  = sg[half][1] + b_in_f[0];
        float m  = fmaxf(c_out, c_in);
        float eo = expf(c_out - m);
        float e2 = expf(c_in  - m);
        float inv = 1.0f / (eo + e2);
        float Cout = (eo * inv) * odm[n] + odmb[n];
        float Cin  = (e2 * inv) * idm[n] + idmb[n];
        sC[half][0] = Cout; sC[half][1] = Cin;
        scbuf[2 * n]     = Cout;
        scbuf[2 * n + 1] = Cin;
        outCout[n] = Cout;
        outCin[n]  = Cin;
    }
    __syncthreads();
    if (gd == 0) {
        float C = sC[half][dir];
        uint2 pw; pw.x = pack2(C * r.x, C * r.y); pw.y = pack2(C * r.z, C * r.w);
        ((dir == 0) ? onb2 : inb2)[(size_t)n * 32 + l] = pw;
    }
}

// MFMA bf16 GEMM. A = [onb | inb | xb] (Cout/Cin pre-folded into onb/inb by
// k_gather; 0.5 folded into W_fc). B^T = bf16 W rows. K = 384 in 6 chunks of 64.
// A-staging is a pure uint4 copy.
__global__ void __launch_bounds__(256) k_gemm(
    const unsigned int* __restrict__ xb32,
    const unsigned int* __restrict__ onb32, const unsigned int* __restrict__ inb32,
    const unsigned short* __restrict__ wbf,
    const float* __restrict__ b_src, const float* __restrict__ b_dst,
    const float* __restrict__ b_fc,
    const float* __restrict__ scbuf,
    float* __restrict__ out)
{
    __shared__ unsigned short sA[MT * 72];    // 64 x (64+8) bf16
    __shared__ unsigned short sBt[DD * 72];   // 128 x (64+8) bf16

    int tid = threadIdx.x;
    int wid = tid >> 6;
    int lane = tid & 63;
    int ml = lane & 15;
    int kq = lane >> 4;
    int n0 = blockIdx.x * MT;

    f32x4 accv[8];
    #pragma unroll
    for (int i = 0; i < 8; i++) accv[i] = (f32x4)0.0f;

    const unsigned int* srcs[3] = { onb32, inb32, xb32 };

    for (int kt = 0; kt < 6; kt++) {
        int srcsel = kt >> 1;
        int k0 = (kt & 1) * 64;
        const unsigned int* S = srcs[srcsel];

        #pragma unroll
        for (int r = 0; r < 2; r++) {
            int s = tid + 256 * r;
            int row = s >> 3;
            int cg = s & 7;
            int gn = n0 + row;
            uint4 p = make_uint4(0u, 0u, 0u, 0u);
            if (gn < NN) {
                p = *(const uint4*)(S + (size_t)gn * 64 + (k0 >> 1) + cg * 4);
            }
            *(uint4*)(sA + row * 72 + cg * 8) = p;
        }
        #pragma unroll
        for (int r = 0; r < 4; r++) {
            int s = tid + 256 * r;
            int row = s >> 3;
            int cg = s & 7;
            uint4 w = *(const uint4*)(wbf + srcsel * 16384 + row * DD + k0 + cg * 8);
            *(uint4*)(sBt + row * 72 + cg * 8) = w;
        }
        __syncthreads();

        #pragma unroll
        for (int ks = 0; ks < 64; ks += 32) {
            short8_t a = *(const short8_t*)(sA + (16 * wid + ml) * 72 + ks + kq * 8);
            #pragma unroll
            for (int i = 0; i < 8; i++) {
                short8_t b = *(const short8_t*)(sBt + (16 * i + ml) * 72 + ks + kq * 8);
                accv[i] = __builtin_amdgcn_mfma_f32_16x16x32_bf16(a, b, accv[i], 0, 0, 0);
            }
        }
        __syncthreads();
    }

    // Epilogue: C/D layout col=lane&15, row=(lane>>4)*4+reg.
    int row_base = n0 + 16 * wid + 4 * kq;
    #pragma unroll
    for (int r = 0; r < 4; r++) {
        int row = row_base + r;
        if (row >= NN) continue;
        float Cout = scbuf[2 * row];
        float Cin  = scbuf[2 * row + 1];
        #pragma unroll
        for (int i = 0; i < 8; i++) {
            int col = 16 * i + ml;
            out[(size_t)row * DD + col] =
                accv[i][r] + Cout * b_src[col] + Cin * b_dst[col] + 0.5f * b_fc[col];
        }
    }
}

extern "C" void kernel_launch(void* const* d_in, const int* in_sizes, int n_in,
                              void* d_out, int out_size, void* d_ws, size_t ws_size,
                              hipStream_t stream) {
    const float* x    = (const float*)d_in[0];
    const int* ei     = (const int*)d_in[1];
    const int* in_degree  = (const int*)d_in[2];
    const int* out_degree = (const int*)d_in[3];
    const float* odm  = (const float*)d_in[4];
    const float* odmb = (const float*)d_in[5];
    const float* idm  = (const float*)d_in[6];
    const float* idmb = (const float*)d_in[7];
    const float* W_src = (const float*)d_in[8];
    const float* b_src = (const float*)d_in[9];
    const float* W_dst = (const float*)d_in[10];
    const float* b_dst = (const float*)d_in[11];
    const float* W_out_f = (const float*)d_in[12];
    const float* b_out_f = (const float*)d_in[13];
    const float* W_in_f  = (const float*)d_in[14];
    const float* b_in_f  = (const float*)d_in[15];
    const float* W_fc    = (const float*)d_in[16];
    const float* b_fc    = (const float*)d_in[17];
    const float* in_tab  = (const float*)d_in[18];
    const float* out_tab = (const float*)d_in[19];

    // WS: [xb N*D u16][onb N*D u16][inb N*D u16][scbuf 2N f32][invb 2N f32]
    //     [wbf 3*16384 u16][cnt 2N i32][bkt_row N*CAP u16][bkt_col N*CAP u16]
    unsigned short* xb  = (unsigned short*)d_ws;
    unsigned short* onb = xb + (size_t)NN * DD;
    unsigned short* inb = onb + (size_t)NN * DD;
    float* scbuf = (float*)(inb + (size_t)NN * DD);
    float* invb  = scbuf + 2 * NN;
    unsigned short* wbf = (unsigned short*)(invb + 2 * NN);
    int* cnt     = (int*)(wbf + 3 * 16384);
    unsigned short* bkt_row = (unsigned short*)(cnt + 2 * NN);
    unsigned short* bkt_col = bkt_row + (size_t)NN * CAP;

    hipMemsetAsync(cnt, 0, (size_t)2 * NN * sizeof(int), stream);

    int conv_quads = (NN * DD + 3 * 16384) / 4;
    k_conv<<<(conv_quads + 255) / 256, 256, 0, stream>>>(x, W_src, W_dst, W_fc, xb, wbf);
    k_place<<<8 * PB, 256, 0, stream>>>(ei, cnt, bkt_row, bkt_col);
    k_inv<<<(2 * NN + 255) / 256, 256, 0, stream>>>(cnt, invb);

    float* o_inv = invb;
    float* i_inv = invb + NN;
    float* out_p  = (float*)d_out;
    float* cin_p  = out_p + (size_t)NN * DD;
    float* cout_p = cin_p + NN;

    k_gather<<<NN / 2, 256, 0, stream>>>((const uint2*)xb, (const float4*)x,
                                         bkt_row, bkt_col, cnt,
                                         o_inv, i_inv, in_degree, out_degree,
                                         odm, odmb, idm, idmb,
                                         (const float4*)W_out_f, b_out_f,
                                         (const float4*)W_in_f, b_in_f,
                                         (const float4*)in_tab, (const float4*)out_tab,
                                         (uint2*)onb, (uint2*)inb,
                                         scbuf, cin_p, cout_p);

    k_gemm<<<(NN + MT - 1) / MT, 256, 0, stream>>>(
        (const unsigned int*)xb, (const unsigned int*)onb, (const unsigned int*)inb,
        wbf, b_src, b_dst, b_fc, scbuf, out_p);
}

// Round 2
// 285.477 us; speedup vs baseline: 1.0428x; 1.0227x over previous
//
#include <hip/hip_runtime.h>

#define NN 50000
#define EE 800000
#define DD 128
#define CAP 48     // bucket capacity; graph degrees ~Poisson(16), P(>=48)~6e-11
#define MT 64      // nodes per gemm block
#define XSL 6250   // nodes per XCD slice (NN/8)
#define PB 128     // place blocks per XCD

typedef short short8_t __attribute__((ext_vector_type(8)));
typedef float f32x4 __attribute__((ext_vector_type(4)));

// f32 -> bf16 (round-to-nearest-even)
__device__ __forceinline__ unsigned short f2bf(float f) {
    union { float f; unsigned int i; } v; v.f = f;
    unsigned int x = v.i;
    x += 0x7FFFu + ((x >> 16) & 1u);
    return (unsigned short)(x >> 16);
}
__device__ __forceinline__ unsigned int pack2(float a, float b) {
    return (unsigned int)f2bf(a) | ((unsigned int)f2bf(b) << 16);
}
// packed bf16 pair -> two f32 (elem0 = low half)
__device__ __forceinline__ float2 bf2x2(unsigned int u) {
    union { unsigned int i; float f; } lo, hi;
    lo.i = u << 16;
    hi.i = u & 0xFFFF0000u;
    return make_float2(lo.f, hi.f);
}

// accumulate 8 bf16 (one uint4 = 16B of a row) into two float4, scaled by w
__device__ __forceinline__ void acc8(float4& a, float4& b, uint4 u, float w) {
    float2 p0 = bf2x2(u.x), p1 = bf2x2(u.y), p2 = bf2x2(u.z), p3 = bf2x2(u.w);
    a.x += w * p0.x; a.y += w * p0.y; a.z += w * p1.x; a.w += w * p1.y;
    b.x += w * p2.x; b.y += w * p2.y; b.z += w * p3.x; b.w += w * p3.y;
}

// Fused bf16 conversion: x (NN*DD floats) then the 3 weight mats (W_fc pre-scaled 0.5).
__global__ void k_conv(const float* __restrict__ x,
                       const float* __restrict__ W_src,
                       const float* __restrict__ W_dst,
                       const float* __restrict__ W_fc,
                       unsigned short* __restrict__ xb,
                       unsigned short* __restrict__ wbf) {
    int t = blockIdx.x * 256 + threadIdx.x;
    int base = t * 4;
    if (base < NN * DD) {
        float4 v = *(const float4*)(x + base);
        uint2 p; p.x = pack2(v.x, v.y); p.y = pack2(v.z, v.w);
        *(uint2*)(xb + base) = p;
    } else {
        int b2 = base - NN * DD;
        if (b2 < 3 * 16384) {
            int src = b2 >> 14;
            int off = b2 & 16383;
            const float* W = (src == 0) ? W_src : (src == 1) ? W_dst : W_fc;
            float sc = (src == 2) ? 0.5f : 1.0f;
            float4 v = *(const float4*)(W + off);
            uint2 p; p.x = pack2(v.x * sc, v.y * sc); p.y = pack2(v.z * sc, v.w * sc);
            *(uint2*)(wbf + b2) = p;
        }
    }
}

// XCD-sliced bucket fill (unchanged): each XCD owns a node slice, scans all edges.
__global__ void __launch_bounds__(256) k_place(
    const int* __restrict__ ei, int* __restrict__ cnt,
    unsigned short* __restrict__ bkt_row, unsigned short* __restrict__ bkt_col) {
    int xcd = blockIdx.x & 7;
    int b   = blockIdx.x >> 3;
    int lo = xcd * XSL, hi = lo + XSL;
    for (int e = b * 256 + threadIdx.x; e < EE; e += PB * 256) {
        int r = ei[e];
        int c = ei[EE + e];
        if (r >= lo && r < hi) {
            int po = atomicAdd(&cnt[r], 1);
            if (po < CAP) bkt_row[(size_t)r * CAP + po] = (unsigned short)c;
        }
        if (c >= lo && c < hi) {
            int pi = atomicAdd(&cnt[NN + c], 1);
            if (pi < CAP) bkt_col[(size_t)c * CAP + pi] = (unsigned short)r;
        }
    }
}

// inv tables + in-dir ratio weights + prescaled xs = bf16(i_inv_or_1 * x).
// A node appearing in bkt_row[n] has in-count>=1 (it received that edge), so the
// out-direction gather is a PURE SUM of xs rows. The in-direction uses
// w2[nb] = o_inv[nb]/s[nb] so w2*xs == o_inv*x exactly (s never 0).
__global__ void __launch_bounds__(256) k_prep(
    const int* __restrict__ cnt, const float4* __restrict__ x4,
    float* __restrict__ invb, float* __restrict__ w2, uint2* __restrict__ xs2)
{
    int t = blockIdx.x * 256 + threadIdx.x;
    if (t < 2 * NN) {
        int d = cnt[t];
        invb[t] = (d > 0) ? (1.0f / sqrtf((float)d)) : 0.0f;
    }
    if (t < NN) {
        int dd = cnt[t];
        int di = cnt[NN + t];
        float o = (dd > 0) ? (1.0f / sqrtf((float)dd)) : 0.0f;
        w2[t] = (di > 0) ? o * sqrtf((float)di) : o;
    }
    if (t < NN * 32) {
        int node = t >> 5;
        int di = cnt[NN + node];
        float s = (di > 0) ? (1.0f / sqrtf((float)di)) : 1.0f;
        float4 v = x4[t];
        uint2 p; p.x = pack2(v.x * s, v.y * s); p.y = pack2(v.z * s, v.w * s);
        xs2[t] = p;
    }
}

// Bucket gather + fused gate. 2 nodes/block; per node 128 threads:
// groups 0-1 gather OUT, groups 2-3 gather IN concurrently. Bucket indices are
// prefetched ONCE per node-dir (1 coalesced uint load, lanes 0-23 cover 48
// entries) and distributed per-row via width-32 __shfl (LDS pipe) -- no
// dependent scalar loads in front of row loads. In-dir weights prefetched
// lane-parallel once. Rows read as 16 lanes x dwordx4 (2 rows per 32-lane
// group per load slot) -- half the loads/addr-calc of 32x8B.
__global__ void __launch_bounds__(256) k_gather(
    const uint4* __restrict__ xs4, const float4* __restrict__ x4,
    const unsigned short* __restrict__ bkt_row, const unsigned short* __restrict__ bkt_col,
    const int* __restrict__ cnt,
    const float* __restrict__ o_inv, const float* __restrict__ i_inv,
    const float* __restrict__ w2,
    const int* __restrict__ in_degree, const int* __restrict__ out_degree,
    const float* __restrict__ odm, const float* __restrict__ odmb,
    const float* __restrict__ idm, const float* __restrict__ idmb,
    const float4* __restrict__ W_out_f4, const float* __restrict__ b_out_f,
    const float4* __restrict__ W_in_f4, const float* __restrict__ b_in_f,
    const float4* __restrict__ in_tab4, const float4* __restrict__ out_tab4,
    uint2* __restrict__ onb2, uint2* __restrict__ inb2,
    float* __restrict__ scbuf,
    float* __restrict__ outCin, float* __restrict__ outCout)
{
    __shared__ float4 sred[2][4][2][16][2];   // [half][g][sub][li][quad]
    __shared__ float sg[2][2];
    __shared__ float sC[2][2];
    int half = threadIdx.x >> 7;
    int n = blockIdx.x * 2 + half;
    int t = threadIdx.x & 127;
    int g = t >> 5;       // 0,1 -> out; 2,3 -> in
    int l = t & 31;
    int dir = g >> 1;
    int gd  = g & 1;
    int sub = l >> 4;     // which of 2 rows this lane serves per load slot
    int li  = l & 15;     // lane within row (16B each)
    int shamt = gd << 4;  // all this group's slots have parity gd

    const unsigned short* bp = ((dir == 0) ? bkt_row : bkt_col) + (size_t)n * CAP;
    int deg = cnt[dir * NN + n]; deg = (deg > CAP) ? CAP : deg;

    // ---- bucket prefetch: 48 u16 entries = 24 uints in lanes 0..23
    unsigned int bw = (l < 24) ? *(const unsigned int*)(bp + 2 * l) : 0u;

    // ---- in-dir weight prefetch: lane j holds w2 for slot j (j<32)
    float w_l = 0.0f;
    if (dir == 1) {
        unsigned int pr = __shfl(bw, l >> 1, 32);
        int il = (pr >> ((l & 1) << 4)) & 0xffff;
        if (l < deg) w_l = w2[il];
    }

    float4 ac0 = make_float4(0.f, 0.f, 0.f, 0.f);
    float4 ac1 = make_float4(0.f, 0.f, 0.f, 0.f);

    if (dir == 0 || deg <= 32) {
        int j = gd;
        // deep: 8 slots/group/iter; lane handles slots j+2*sub+4k, k=0..3
        for (; j + 14 < deg; j += 16) {
            int s0 = j + 2 * sub, s1 = s0 + 4, s2 = s0 + 8, s3 = s0 + 12;
            int i0 = (__shfl(bw, s0 >> 1, 32) >> shamt) & 0xffff;
            int i1 = (__shfl(bw, s1 >> 1, 32) >> shamt) & 0xffff;
            int i2 = (__shfl(bw, s2 >> 1, 32) >> shamt) & 0xffff;
            int i3 = (__shfl(bw, s3 >> 1, 32) >> shamt) & 0xffff;
            uint4 u0 = xs4[(size_t)i0 * 16 + li];
            uint4 u1 = xs4[(size_t)i1 * 16 + li];
            uint4 u2 = xs4[(size_t)i2 * 16 + li];
            uint4 u3 = xs4[(size_t)i3 * 16 + li];
            float w0 = 1.f, w1 = 1.f, w2v = 1.f, w3 = 1.f;
            if (dir) {
                w0  = __shfl(w_l, s0, 32);
                w1  = __shfl(w_l, s1, 32);
                w2v = __shfl(w_l, s2, 32);
                w3  = __shfl(w_l, s3, 32);
            }
            acc8(ac0, ac1, u0, w0);
            acc8(ac0, ac1, u1, w1);
            acc8(ac0, ac1, u2, w2v);
            acc8(ac0, ac1, u3, w3);
        }
        // mid: 4 slots/group/iter
        for (; j + 6 < deg; j += 8) {
            int s0 = j + 2 * sub, s1 = s0 + 4;
            int i0 = (__shfl(bw, s0 >> 1, 32) >> shamt) & 0xffff;
            int i1 = (__shfl(bw, s1 >> 1, 32) >> shamt) & 0xffff;
            uint4 u0 = xs4[(size_t)i0 * 16 + li];
            uint4 u1 = xs4[(size_t)i1 * 16 + li];
            float w0 = 1.f, w1 = 1.f;
            if (dir) {
                w0 = __shfl(w_l, s0, 32);
                w1 = __shfl(w_l, s1, 32);
            }
            acc8(ac0, ac1, u0, w0);
            acc8(ac0, ac1, u1, w1);
        }
        // tail: 2 slots/iter, predicated; shfls hoisted out of the predicate
        for (; j < deg; j += 4) {
            int s0 = j + 2 * sub;
            int sc = (s0 < deg) ? s0 : gd;   // deg>gd holds (j<deg, j>=gd)
            int i0 = (__shfl(bw, sc >> 1, 32) >> shamt) & 0xffff;
            float w0 = 1.f;
            if (dir) w0 = __shfl(w_l, sc, 32);
            if (s0 < deg) {
                uint4 u0 = xs4[(size_t)i0 * 16 + li];
                acc8(ac0, ac1, u0, w0);
            }
        }
    } else {
        // rare (P~1e-4): in-dir with deg>32 -- direct weight loads
        for (int j = gd; j < deg; j += 4) {
            int s0 = j + 2 * sub;
            int sc = (s0 < deg) ? s0 : gd;
            int i0 = (__shfl(bw, sc >> 1, 32) >> shamt) & 0xffff;
            if (s0 < deg) {
                float w0 = w2[i0];
                uint4 u0 = xs4[(size_t)i0 * 16 + li];
                acc8(ac0, ac1, u0, w0);
            }
        }
    }

    sred[half][g][sub][li][0] = ac0;
    sred[half][g][sub][li][1] = ac1;
    __syncthreads();

    float4 r = make_float4(0.f, 0.f, 0.f, 0.f);
    if (gd == 0) {
        // reduction lane l covers cols 4l..4l+3: src lane li=l>>1, quad l&1
        int src = l >> 1, q = l & 1;
        int g0 = dir * 2;
        float4 b0 = sred[half][g0][0][src][q];
        float4 b1 = sred[half][g0][1][src][q];
        float4 b2 = sred[half][g0 + 1][0][src][q];
        float4 b3 = sred[half][g0 + 1][1][src][q];
        float wn = (dir == 0) ? o_inv[n] : i_inv[n];
        r.x = wn * (b0.x + b1.x + b2.x + b3.x);
        r.y = wn * (b0.y + b1.y + b2.y + b3.y);
        r.z = wn * (b0.z + b1.z + b2.z + b3.z);
        r.w = wn * (b0.w + b1.w + b2.w + b3.w);
        float4 xv = x4[(size_t)n * 32 + l];
        float4 tb, wf;
        if (dir == 0) {
            int odg = out_degree[n];
            odg = (odg < 0) ? 0 : (odg > 63 ? 63 : odg);
            tb = out_tab4[(size_t)odg * 32 + l];
            wf = W_out_f4[l];
        } else {
            int idg = in_degree[n];
            idg = (idg < 0) ? 0 : (idg > 63 ? 63 : idg);
            tb = in_tab4[(size_t)idg * 32 + l];
            wf = W_in_f4[l];
        }
        float p = (r.x - xv.x + tb.x) * wf.x + (r.y - xv.y + tb.y) * wf.y
                + (r.z - xv.z + tb.z) * wf.z + (r.w - xv.w + tb.w) * wf.w;
        #pragma unroll
        for (int off = 16; off > 0; off >>= 1) p += __shfl_down(p, off);
        if (l == 0) sg[half][dir] = p;
    }
    __syncthreads();
    if (t == 0) {
        float c_out = sg[half][0] + b_out_f[0];
        float c_in  = sg[half][1] + b_in_f[0];
        float m  = fmaxf(c_out, c_in);
        float eo = expf(c_out - m);
        float e2 = expf(c_in  - m);
        float inv = 1.0f / (eo + e2);
        float Cout = (eo * inv) * odm[n] + odmb[n];
        float Cin  = (e2 * inv) * idm[n] + idmb[n];
        sC[half][0] = Cout; sC[half][1] = Cin;
        scbuf[2 * n]     = Cout;
        scbuf[2 * n + 1] = Cin;
        outCout[n] = Cout;
        outCin[n]  = Cin;
    }
    __syncthreads();
    if (gd == 0) {
        float C = sC[half][dir];
        uint2 pw; pw.x = pack2(C * r.x, C * r.y); pw.y = pack2(C * r.z, C * r.w);
        ((dir == 0) ? onb2 : inb2)[(size_t)n * 32 + l] = pw;
    }
}

// MFMA bf16 GEMM. A = [onb | inb | xb] (Cout/Cin pre-folded into onb/inb by
// k_gather; 0.5 folded into W_fc). B^T = bf16 W rows. K = 384 in 6 chunks of 64.
__global__ void __launch_bounds__(256) k_gemm(
    const unsigned int* __restrict__ xb32,
    const unsigned int* __restrict__ onb32, const unsigned int* __restrict__ inb32,
    const unsigned short* __restrict__ wbf,
    const float* __restrict__ b_src, const float* __restrict__ b_dst,
    const float* __restrict__ b_fc,
    const float* __restrict__ scbuf,
    float* __restrict__ out)
{
    __shared__ unsigned short sA[MT * 72];    // 64 x (64+8) bf16
    __shared__ unsigned short sBt[DD * 72];   // 128 x (64+8) bf16

    int tid = threadIdx.x;
    int wid = tid >> 6;
    int lane = tid & 63;
    int ml = lane & 15;
    int kq = lane >> 4;
    int n0 = blockIdx.x * MT;

    f32x4 accv[8];
    #pragma unroll
    for (int i = 0; i < 8; i++) accv[i] = (f32x4)0.0f;

    const unsigned int* srcs[3] = { onb32, inb32, xb32 };

    for (int kt = 0; kt < 6; kt++) {
        int srcsel = kt >> 1;
        int k0 = (kt & 1) * 64;
        const unsigned int* S = srcs[srcsel];

        #pragma unroll
        for (int r = 0; r < 2; r++) {
            int s = tid + 256 * r;
            int row = s >> 3;
            int cg = s & 7;
            int gn = n0 + row;
            uint4 p = make_uint4(0u, 0u, 0u, 0u);
            if (gn < NN) {
                p = *(const uint4*)(S + (size_t)gn * 64 + (k0 >> 1) + cg * 4);
            }
            *(uint4*)(sA + row * 72 + cg * 8) = p;
        }
        #pragma unroll
        for (int r = 0; r < 4; r++) {
            int s = tid + 256 * r;
            int row = s >> 3;
            int cg = s & 7;
            uint4 w = *(const uint4*)(wbf + srcsel * 16384 + row * DD + k0 + cg * 8);
            *(uint4*)(sBt + row * 72 + cg * 8) = w;
        }
        __syncthreads();

        #pragma unroll
        for (int ks = 0; ks < 64; ks += 32) {
            short8_t a = *(const short8_t*)(sA + (16 * wid + ml) * 72 + ks + kq * 8);
            #pragma unroll
            for (int i = 0; i < 8; i++) {
                short8_t b = *(const short8_t*)(sBt + (16 * i + ml) * 72 + ks + kq * 8);
                accv[i] = __builtin_amdgcn_mfma_f32_16x16x32_bf16(a, b, accv[i], 0, 0, 0);
            }
        }
        __syncthreads();
    }

    // Epilogue: C/D layout col=lane&15, row=(lane>>4)*4+reg.
    int row_base = n0 + 16 * wid + 4 * kq;
    #pragma unroll
    for (int r = 0; r < 4; r++) {
        int row = row_base + r;
        if (row >= NN) continue;
        float Cout = scbuf[2 * row];
        float Cin  = scbuf[2 * row + 1];
        #pragma unroll
        for (int i = 0; i < 8; i++) {
            int col = 16 * i + ml;
            out[(size_t)row * DD + col] =
                accv[i][r] + Cout * b_src[col] + Cin * b_dst[col] + 0.5f * b_fc[col];
        }
    }
}

extern "C" void kernel_launch(void* const* d_in, const int* in_sizes, int n_in,
                              void* d_out, int out_size, void* d_ws, size_t ws_size,
                              hipStream_t stream) {
    const float* x    = (const float*)d_in[0];
    const int* ei     = (const int*)d_in[1];
    const int* in_degree  = (const int*)d_in[2];
    const int* out_degree = (const int*)d_in[3];
    const float* odm  = (const float*)d_in[4];
    const float* odmb = (const float*)d_in[5];
    const float* idm  = (const float*)d_in[6];
    const float* idmb = (const float*)d_in[7];
    const float* W_src = (const float*)d_in[8];
    const float* b_src = (const float*)d_in[9];
    const float* W_dst = (const float*)d_in[10];
    const float* b_dst = (const float*)d_in[11];
    const float* W_out_f = (const float*)d_in[12];
    const float* b_out_f = (const float*)d_in[13];
    const float* W_in_f  = (const float*)d_in[14];
    const float* b_in_f  = (const float*)d_in[15];
    const float* W_fc    = (const float*)d_in[16];
    const float* b_fc    = (const float*)d_in[17];
    const float* in_tab  = (const float*)d_in[18];
    const float* out_tab = (const float*)d_in[19];

    // WS: [xb N*D u16][onb N*D u16][inb N*D u16][xs N*D u16][scbuf 2N f32]
    //     [invb 2N f32][w2 N f32][wbf 3*16384 u16][cnt 2N i32]
    //     [bkt_row N*CAP u16][bkt_col N*CAP u16]   (~62.3 MB)
    unsigned short* xb  = (unsigned short*)d_ws;
    unsigned short* onb = xb + (size_t)NN * DD;
    unsigned short* inb = onb + (size_t)NN * DD;
    unsigned short* xs  = inb + (size_t)NN * DD;
    float* scbuf = (float*)(xs + (size_t)NN * DD);
    float* invb  = scbuf + 2 * NN;
    float* w2    = invb + 2 * NN;
    unsigned short* wbf = (unsigned short*)(w2 + NN);
    int* cnt     = (int*)(wbf + 3 * 16384);
    unsigned short* bkt_row = (unsigned short*)(cnt + 2 * NN);
    unsigned short* bkt_col = bkt_row + (size_t)NN * CAP;

    hipMemsetAsync(cnt, 0, (size_t)2 * NN * sizeof(int), stream);

    int conv_quads = (NN * DD + 3 * 16384) / 4;
    k_conv<<<(conv_quads + 255) / 256, 256, 0, stream>>>(x, W_src, W_dst, W_fc, xb, wbf);
    k_place<<<8 * PB, 256, 0, stream>>>(ei, cnt, bkt_row, bkt_col);
    k_prep<<<(NN * 32 + 255) / 256, 256, 0, stream>>>(cnt, (const float4*)x,
                                                      invb, w2, (uint2*)xs);

    float* o_inv = invb;
    float* i_inv = invb + NN;
    float* out_p  = (float*)d_out;
    float* cin_p  = out_p + (size_t)NN * DD;
    float* cout_p = cin_p + NN;

    k_gather<<<NN / 2, 256, 0, stream>>>((const uint4*)xs, (const float4*)x,
                                         bkt_row, bkt_col, cnt,
                                         o_inv, i_inv, w2, in_degree, out_degree,
                                         odm, odmb, idm, idmb,
                                         (const float4*)W_out_f, b_out_f,
                                         (const float4*)W_in_f, b_in_f,
                                         (const float4*)in_tab, (const float4*)out_tab,
                                         (uint2*)onb, (uint2*)inb,
                                         scbuf, cin_p, cout_p);

    k_gemm<<<(NN + MT - 1) / MT, 256, 0, stream>>>(
        (const unsigned int*)xb, (const unsigned int*)onb, (const unsigned int*)inb,
        wbf, b_src, b_dst, b_fc, scbuf, out_p);
}

// Round 3
// 275.131 us; speedup vs baseline: 1.0820x; 1.0376x over previous
//
#include <hip/hip_runtime.h>

#define NN 50000
#define EE 800000
#define DD 128
#define CAP 48     // bucket capacity; graph degrees ~Poisson(16), P(>=48)~6e-11
#define MT 64      // nodes per gemm block
#define XSL 6250   // nodes per XCD slice (NN/8)
#define PB 128     // place blocks per XCD
#define PCB (8 * PB)

typedef short short8_t __attribute__((ext_vector_type(8)));
typedef float f32x4 __attribute__((ext_vector_type(4)));
typedef float f32x2 __attribute__((ext_vector_type(2)));

// f32 -> bf16 (round-to-nearest-even)
__device__ __forceinline__ unsigned short f2bf(float f) {
    union { float f; unsigned int i; } v; v.f = f;
    unsigned int x = v.i;
    x += 0x7FFFu + ((x >> 16) & 1u);
    return (unsigned short)(x >> 16);
}
__device__ __forceinline__ unsigned int pack2(float a, float b) {
    return (unsigned int)f2bf(a) | ((unsigned int)f2bf(b) << 16);
}
// packed bf16 pair -> two f32 (elem0 = low half)
__device__ __forceinline__ float2 bf2x2(unsigned int u) {
    union { unsigned int i; float f; } lo, hi;
    lo.i = u << 16;
    hi.i = u & 0xFFFF0000u;
    return make_float2(lo.f, hi.f);
}
// packed bf16 pair -> f32x2 (for packed-math accumulate)
__device__ __forceinline__ f32x2 bfup(unsigned int u) {
    union { unsigned int i; float f; } lo, hi;
    lo.i = u << 16;
    hi.i = u & 0xFFFF0000u;
    f32x2 r; r.x = lo.f; r.y = hi.f;
    return r;
}
// packed f32 math: 2 FMAs (or adds) per instruction issue
__device__ __forceinline__ void pkadd(f32x2& a, f32x2 b) {
    asm("v_pk_add_f32 %0, %1, %0" : "+v"(a) : "v"(b));
}
__device__ __forceinline__ void pkfma(f32x2& a, f32x2 b, f32x2 w) {
    asm("v_pk_fma_f32 %0, %1, %2, %0" : "+v"(a) : "v"(b), "v"(w));
}
__device__ __forceinline__ void accnw(f32x2* ac, uint4 u) {
    pkadd(ac[0], bfup(u.x)); pkadd(ac[1], bfup(u.y));
    pkadd(ac[2], bfup(u.z)); pkadd(ac[3], bfup(u.w));
}
__device__ __forceinline__ void accw(f32x2* ac, uint4 u, float w) {
    f32x2 wp; wp.x = w; wp.y = w;
    pkfma(ac[0], bfup(u.x), wp); pkfma(ac[1], bfup(u.y), wp);
    pkfma(ac[2], bfup(u.z), wp); pkfma(ac[3], bfup(u.w), wp);
}

// Fused place + conv. Blocks [0, PCB): XCD-sliced bucket fill (atomic-latency
// bound). Blocks [PCB, ...): bf16 conversion of x and the 3 weight mats
// (BW-bound) -- the streaming hides under the place blocks' atomic latency.
__global__ void __launch_bounds__(256) k_pc(
    const int* __restrict__ ei, int* __restrict__ cnt,
    unsigned short* __restrict__ bkt_row, unsigned short* __restrict__ bkt_col,
    const float* __restrict__ x,
    const float* __restrict__ W_src, const float* __restrict__ W_dst,
    const float* __restrict__ W_fc,
    unsigned short* __restrict__ xb, unsigned short* __restrict__ wbf)
{
    if (blockIdx.x < PCB) {
        int xcd = blockIdx.x & 7;
        int b   = blockIdx.x >> 3;
        int lo = xcd * XSL, hi = lo + XSL;
        for (int e = b * 256 + threadIdx.x; e < EE; e += PB * 256) {
            int r = ei[e];
            int c = ei[EE + e];
            if (r >= lo && r < hi) {
                int po = atomicAdd(&cnt[r], 1);
                if (po < CAP) bkt_row[(size_t)r * CAP + po] = (unsigned short)c;
            }
            if (c >= lo && c < hi) {
                int pi = atomicAdd(&cnt[NN + c], 1);
                if (pi < CAP) bkt_col[(size_t)c * CAP + pi] = (unsigned short)r;
            }
        }
    } else {
        int t = (blockIdx.x - PCB) * 256 + threadIdx.x;
        int base = t * 4;
        if (base < NN * DD) {
            float4 v = *(const float4*)(x + base);
            uint2 p; p.x = pack2(v.x, v.y); p.y = pack2(v.z, v.w);
            *(uint2*)(xb + base) = p;
        } else {
            int b2 = base - NN * DD;
            if (b2 < 3 * 16384) {
                int src = b2 >> 14;
                int off = b2 & 16383;
                const float* W = (src == 0) ? W_src : (src == 1) ? W_dst : W_fc;
                float sc = (src == 2) ? 0.5f : 1.0f;
                float4 v = *(const float4*)(W + off);
                uint2 p; p.x = pack2(v.x * sc, v.y * sc); p.y = pack2(v.z * sc, v.w * sc);
                *(uint2*)(wbf + b2) = p;
            }
        }
    }
}

// inv tables + in-dir ratio weights + prescaled xs = bf16(i_inv_or_1 * x).
// A node appearing in bkt_row[n] has in-count>=1 (it received that edge), so the
// out-direction gather is a PURE SUM of xs rows. The in-direction uses
// w2[nb] = o_inv[nb]/s[nb] so w2*xs == o_inv*x exactly (s never 0).
__global__ void __launch_bounds__(256) k_prep(
    const int* __restrict__ cnt, const float4* __restrict__ x4,
    float* __restrict__ invb, float* __restrict__ w2, uint2* __restrict__ xs2)
{
    int t = blockIdx.x * 256 + threadIdx.x;
    if (t < 2 * NN) {
        int d = cnt[t];
        invb[t] = (d > 0) ? (1.0f / sqrtf((float)d)) : 0.0f;
    }
    if (t < NN) {
        int dd = cnt[t];
        int di = cnt[NN + t];
        float o = (dd > 0) ? (1.0f / sqrtf((float)dd)) : 0.0f;
        w2[t] = (di > 0) ? o * sqrtf((float)di) : o;
    }
    if (t < NN * 32) {
        int node = t >> 5;
        int di = cnt[NN + node];
        float s = (di > 0) ? (1.0f / sqrtf((float)di)) : 1.0f;
        float4 v = x4[t];
        uint2 p; p.x = pack2(v.x * s, v.y * s); p.y = pack2(v.z * s, v.w * s);
        xs2[t] = p;
    }
}

// Bucket gather + fused gate. 2 nodes/block; per node 128 threads: wave-half
// 0-63 gathers OUT, 64-127 gathers IN (dir is wave-uniform -> scalar branch).
// Bucket indices prefetched once (1 coalesced load, lanes 0-23) and spread via
// width-32 shfl. Rows read as 16 lanes x dwordx4. OUT dir: pure packed-add of
// prescaled xs rows (no weights). IN dir: packed-fma with w2 ratio weights.
__global__ void __launch_bounds__(256) k_gather(
    const uint4* __restrict__ xs4, const float4* __restrict__ x4,
    const unsigned short* __restrict__ bkt_row, const unsigned short* __restrict__ bkt_col,
    const int* __restrict__ cnt,
    const float* __restrict__ o_inv, const float* __restrict__ i_inv,
    const float* __restrict__ w2,
    const int* __restrict__ in_degree, const int* __restrict__ out_degree,
    const float* __restrict__ odm, const float* __restrict__ odmb,
    const float* __restrict__ idm, const float* __restrict__ idmb,
    const float4* __restrict__ W_out_f4, const float* __restrict__ b_out_f,
    const float4* __restrict__ W_in_f4, const float* __restrict__ b_in_f,
    const float4* __restrict__ in_tab4, const float4* __restrict__ out_tab4,
    uint2* __restrict__ onb2, uint2* __restrict__ inb2,
    float* __restrict__ scbuf,
    float* __restrict__ outCin, float* __restrict__ outCout)
{
    __shared__ float4 sred[2][4][2][16][3];   // [half][g][sub][li][quad(+pad)]
    __shared__ float sg[2][2];
    __shared__ float sC[2][2];
    int half = threadIdx.x >> 7;
    int n = blockIdx.x * 2 + half;
    int t = threadIdx.x & 127;
    int g = t >> 5;       // 0,1 -> out; 2,3 -> in
    int l = t & 31;
    int dir = g >> 1;     // wave-uniform
    int gd  = g & 1;
    int sub = l >> 4;     // which of 2 rows this lane serves per load slot
    int li  = l & 15;     // lane within row (16B each)
    int shamt = gd << 4;  // all this group's slots have parity gd

    const unsigned short* bp = ((dir == 0) ? bkt_row : bkt_col) + (size_t)n * CAP;
    int deg = cnt[dir * NN + n]; deg = (deg > CAP) ? CAP : deg;

    // ---- bucket prefetch: 48 u16 entries = 24 uints in lanes 0..23
    unsigned int bw = (l < 24) ? *(const unsigned int*)(bp + 2 * l) : 0u;

    // ---- in-dir weight prefetch: lane j holds w2 for slot j (j<32)
    float w_l = 0.0f;
    if (dir == 1) {
        unsigned int pr = __shfl(bw, l >> 1, 32);
        int il = (pr >> ((l & 1) << 4)) & 0xffff;
        if (l < deg) w_l = w2[il];
    }

    f32x2 ac[4];
    ac[0] = (f32x2)0.0f; ac[1] = (f32x2)0.0f; ac[2] = (f32x2)0.0f; ac[3] = (f32x2)0.0f;

    if (dir == 0) {
        // ---- OUT: pure sum of prescaled rows (packed adds, no weights)
        int j = gd;
        for (; j + 14 < deg; j += 16) {
            int s0 = j + 2 * sub;
            int i0 = (__shfl(bw, s0 >> 1, 32) >> shamt) & 0xffff;
            int i1 = (__shfl(bw, (s0 + 4) >> 1, 32) >> shamt) & 0xffff;
            int i2 = (__shfl(bw, (s0 + 8) >> 1, 32) >> shamt) & 0xffff;
            int i3 = (__shfl(bw, (s0 + 12) >> 1, 32) >> shamt) & 0xffff;
            uint4 u0 = xs4[(size_t)i0 * 16 + li];
            uint4 u1 = xs4[(size_t)i1 * 16 + li];
            uint4 u2 = xs4[(size_t)i2 * 16 + li];
            uint4 u3 = xs4[(size_t)i3 * 16 + li];
            accnw(ac, u0); accnw(ac, u1); accnw(ac, u2); accnw(ac, u3);
        }
        for (; j + 6 < deg; j += 8) {
            int s0 = j + 2 * sub;
            int i0 = (__shfl(bw, s0 >> 1, 32) >> shamt) & 0xffff;
            int i1 = (__shfl(bw, (s0 + 4) >> 1, 32) >> shamt) & 0xffff;
            uint4 u0 = xs4[(size_t)i0 * 16 + li];
            uint4 u1 = xs4[(size_t)i1 * 16 + li];
            accnw(ac, u0); accnw(ac, u1);
        }
        for (; j < deg; j += 4) {
            int s0 = j + 2 * sub;
            int sc = (s0 < deg) ? s0 : gd;
            int i0 = (__shfl(bw, sc >> 1, 32) >> shamt) & 0xffff;
            if (s0 < deg) {
                uint4 u0 = xs4[(size_t)i0 * 16 + li];
                accnw(ac, u0);
            }
        }
    } else if (deg <= 32) {
        // ---- IN: packed fma with shfl-distributed w2 weights
        int j = gd;
        for (; j + 14 < deg; j += 16) {
            int s0 = j + 2 * sub, s1 = s0 + 4, s2 = s0 + 8, s3 = s0 + 12;
            int i0 = (__shfl(bw, s0 >> 1, 32) >> shamt) & 0xffff;
            int i1 = (__shfl(bw, s1 >> 1, 32) >> shamt) & 0xffff;
            int i2 = (__shfl(bw, s2 >> 1, 32) >> shamt) & 0xffff;
            int i3 = (__shfl(bw, s3 >> 1, 32) >> shamt) & 0xffff;
            uint4 u0 = xs4[(size_t)i0 * 16 + li];
            uint4 u1 = xs4[(size_t)i1 * 16 + li];
            uint4 u2 = xs4[(size_t)i2 * 16 + li];
            uint4 u3 = xs4[(size_t)i3 * 16 + li];
            float w0 = __shfl(w_l, s0, 32);
            float w1 = __shfl(w_l, s1, 32);
            float w2v = __shfl(w_l, s2, 32);
            float w3 = __shfl(w_l, s3, 32);
            accw(ac, u0, w0); accw(ac, u1, w1); accw(ac, u2, w2v); accw(ac, u3, w3);
        }
        for (; j + 6 < deg; j += 8) {
            int s0 = j + 2 * sub, s1 = s0 + 4;
            int i0 = (__shfl(bw, s0 >> 1, 32) >> shamt) & 0xffff;
            int i1 = (__shfl(bw, s1 >> 1, 32) >> shamt) & 0xffff;
            uint4 u0 = xs4[(size_t)i0 * 16 + li];
            uint4 u1 = xs4[(size_t)i1 * 16 + li];
            float w0 = __shfl(w_l, s0, 32);
            float w1 = __shfl(w_l, s1, 32);
            accw(ac, u0, w0); accw(ac, u1, w1);
        }
        for (; j < deg; j += 4) {
            int s0 = j + 2 * sub;
            int sc = (s0 < deg) ? s0 : gd;
            int i0 = (__shfl(bw, sc >> 1, 32) >> shamt) & 0xffff;
            float w0 = __shfl(w_l, sc, 32);
            if (s0 < deg) {
                uint4 u0 = xs4[(size_t)i0 * 16 + li];
                accw(ac, u0, w0);
            }
        }
    } else {
        // rare (P~1e-4): in-dir with deg>32 -- direct weight loads
        for (int j = gd; j < deg; j += 4) {
            int s0 = j + 2 * sub;
            int sc = (s0 < deg) ? s0 : gd;
            int i0 = (__shfl(bw, sc >> 1, 32) >> shamt) & 0xffff;
            if (s0 < deg) {
                float w0 = w2[i0];
                uint4 u0 = xs4[(size_t)i0 * 16 + li];
                accw(ac, u0, w0);
            }
        }
    }

    sred[half][g][sub][li][0] = make_float4(ac[0].x, ac[0].y, ac[1].x, ac[1].y);
    sred[half][g][sub][li][1] = make_float4(ac[2].x, ac[2].y, ac[3].x, ac[3].y);
    __syncthreads();

    float4 r = make_float4(0.f, 0.f, 0.f, 0.f);
    if (gd == 0) {
        // reduction lane l covers cols 4l..4l+3: src lane li=l>>1, quad l&1
        int src = l >> 1, q = l & 1;
        int g0 = dir * 2;
        float4 b0 = sred[half][g0][0][src][q];
        float4 b1 = sred[half][g0][1][src][q];
        float4 b2 = sred[half][g0 + 1][0][src][q];
        float4 b3 = sred[half][g0 + 1][1][src][q];
        float wn = (dir == 0) ? o_inv[n] : i_inv[n];
        r.x = wn * (b0.x + b1.x + b2.x + b3.x);
        r.y = wn * (b0.y + b1.y + b2.y + b3.y);
        r.z = wn * (b0.z + b1.z + b2.z + b3.z);
        r.w = wn * (b0.w + b1.w + b2.w + b3.w);
        float4 xv = x4[(size_t)n * 32 + l];
        float4 tb, wf;
        if (dir == 0) {
            int odg = out_degree[n];
            odg = (odg < 0) ? 0 : (odg > 63 ? 63 : odg);
            tb = out_tab4[(size_t)odg * 32 + l];
            wf = W_out_f4[l];
        } else {
            int idg = in_degree[n];
            idg = (idg < 0) ? 0 : (idg > 63 ? 63 : idg);
            tb = in_tab4[(size_t)idg * 32 + l];
            wf = W_in_f4[l];
        }
        float p = (r.x - xv.x + tb.x) * wf.x + (r.y - xv.y + tb.y) * wf.y
                + (r.z - xv.z + tb.z) * wf.z + (r.w - xv.w + tb.w) * wf.w;
        #pragma unroll
        for (int off = 16; off > 0; off >>= 1) p += __shfl_down(p, off);
        if (l == 0) sg[half][dir] = p;
    }
    __syncthreads();
    if (t == 0) {
        float c_out = sg[half][0] + b_out_f[0];
        float c_in  = sg[half][1] + b_in_f[0];
        float m  = fmaxf(c_out, c_in);
        float eo = expf(c_out - m);
        float e2 = expf(c_in  - m);
        float inv = 1.0f / (eo + e2);
        float Cout = (eo * inv) * odm[n] + odmb[n];
        float Cin  = (e2 * inv) * idm[n] + idmb[n];
        sC[half][0] = Cout; sC[half][1] = Cin;
        scbuf[2 * n]     = Cout;
        scbuf[2 * n + 1] = Cin;
        outCout[n] = Cout;
        outCin[n]  = Cin;
    }
    __syncthreads();
    if (gd == 0) {
        float C = sC[half][dir];
        uint2 pw; pw.x = pack2(C * r.x, C * r.y); pw.y = pack2(C * r.z, C * r.w);
        ((dir == 0) ? onb2 : inb2)[(size_t)n * 32 + l] = pw;
    }
}

// MFMA bf16 GEMM. A = [onb | inb | xb] (Cout/Cin pre-folded into onb/inb by
// k_gather; 0.5 folded into W_fc). B^T = bf16 W rows. K = 384 in 6 chunks of 64.
__global__ void __launch_bounds__(256) k_gemm(
    const unsigned int* __restrict__ xb32,
    const unsigned int* __restrict__ onb32, const unsigned int* __restrict__ inb32,
    const unsigned short* __restrict__ wbf,
    const float* __restrict__ b_src, const float* __restrict__ b_dst,
    const float* __restrict__ b_fc,
    const float* __restrict__ scbuf,
    float* __restrict__ out)
{
    __shared__ unsigned short sA[MT * 72];    // 64 x (64+8) bf16
    __shared__ unsigned short sBt[DD * 72];   // 128 x (64+8) bf16

    int tid = threadIdx.x;
    int wid = tid >> 6;
    int lane = tid & 63;
    int ml = lane & 15;
    int kq = lane >> 4;
    int n0 = blockIdx.x * MT;

    f32x4 accv[8];
    #pragma unroll
    for (int i = 0; i < 8; i++) accv[i] = (f32x4)0.0f;

    const unsigned int* srcs[3] = { onb32, inb32, xb32 };

    for (int kt = 0; kt < 6; kt++) {
        int srcsel = kt >> 1;
        int k0 = (kt & 1) * 64;
        const unsigned int* S = srcs[srcsel];

        #pragma unroll
        for (int r = 0; r < 2; r++) {
            int s = tid + 256 * r;
            int row = s >> 3;
            int cg = s & 7;
            int gn = n0 + row;
            uint4 p = make_uint4(0u, 0u, 0u, 0u);
            if (gn < NN) {
                p = *(const uint4*)(S + (size_t)gn * 64 + (k0 >> 1) + cg * 4);
            }
            *(uint4*)(sA + row * 72 + cg * 8) = p;
        }
        #pragma unroll
        for (int r = 0; r < 4; r++) {
            int s = tid + 256 * r;
            int row = s >> 3;
            int cg = s & 7;
            uint4 w = *(const uint4*)(wbf + srcsel * 16384 + row * DD + k0 + cg * 8);
            *(uint4*)(sBt + row * 72 + cg * 8) = w;
        }
        __syncthreads();

        #pragma unroll
        for (int ks = 0; ks < 64; ks += 32) {
            short8_t a = *(const short8_t*)(sA + (16 * wid + ml) * 72 + ks + kq * 8);
            #pragma unroll
            for (int i = 0; i < 8; i++) {
                short8_t b = *(const short8_t*)(sBt + (16 * i + ml) * 72 + ks + kq * 8);
                accv[i] = __builtin_amdgcn_mfma_f32_16x16x32_bf16(a, b, accv[i], 0, 0, 0);
            }
        }
        __syncthreads();
    }

    // Epilogue: C/D layout col=lane&15, row=(lane>>4)*4+reg.
    int row_base = n0 + 16 * wid + 4 * kq;
    #pragma unroll
    for (int r = 0; r < 4; r++) {
        int row = row_base + r;
        if (row >= NN) continue;
        float Cout = scbuf[2 * row];
        float Cin  = scbuf[2 * row + 1];
        #pragma unroll
        for (int i = 0; i < 8; i++) {
            int col = 16 * i + ml;
            out[(size_t)row * DD + col] =
                accv[i][r] + Cout * b_src[col] + Cin * b_dst[col] + 0.5f * b_fc[col];
        }
    }
}

extern "C" void kernel_launch(void* const* d_in, const int* in_sizes, int n_in,
                              void* d_out, int out_size, void* d_ws, size_t ws_size,
                              hipStream_t stream) {
    const float* x    = (const float*)d_in[0];
    const int* ei     = (const int*)d_in[1];
    const int* in_degree  = (const int*)d_in[2];
    const int* out_degree = (const int*)d_in[3];
    const float* odm  = (const float*)d_in[4];
    const float* odmb = (const float*)d_in[5];
    const float* idm  = (const float*)d_in[6];
    const float* idmb = (const float*)d_in[7];
    const float* W_src = (const float*)d_in[8];
    const float* b_src = (const float*)d_in[9];
    const float* W_dst = (const float*)d_in[10];
    const float* b_dst = (const float*)d_in[11];
    const float* W_out_f = (const float*)d_in[12];
    const float* b_out_f = (const float*)d_in[13];
    const float* W_in_f  = (const float*)d_in[14];
    const float* b_in_f  = (const float*)d_in[15];
    const float* W_fc    = (const float*)d_in[16];
    const float* b_fc    = (const float*)d_in[17];
    const float* in_tab  = (const float*)d_in[18];
    const float* out_tab = (const float*)d_in[19];

    // WS: [xb N*D u16][onb N*D u16][inb N*D u16][xs N*D u16][scbuf 2N f32]
    //     [invb 2N f32][w2 N f32][wbf 3*16384 u16][cnt 2N i32]
    //     [bkt_row N*CAP u16][bkt_col N*CAP u16]   (~62.3 MB)
    unsigned short* xb  = (unsigned short*)d_ws;
    unsigned short* onb = xb + (size_t)NN * DD;
    unsigned short* inb = onb + (size_t)NN * DD;
    unsigned short* xs  = inb + (size_t)NN * DD;
    float* scbuf = (float*)(xs + (size_t)NN * DD);
    float* invb  = scbuf + 2 * NN;
    float* w2    = invb + 2 * NN;
    unsigned short* wbf = (unsigned short*)(w2 + NN);
    int* cnt     = (int*)(wbf + 3 * 16384);
    unsigned short* bkt_row = (unsigned short*)(cnt + 2 * NN);
    unsigned short* bkt_col = bkt_row + (size_t)NN * CAP;

    hipMemsetAsync(cnt, 0, (size_t)2 * NN * sizeof(int), stream);

    int conv_quads = (NN * DD + 3 * 16384) / 4;
    int conv_blocks = (conv_quads + 255) / 256;
    k_pc<<<PCB + conv_blocks, 256, 0, stream>>>(ei, cnt, bkt_row, bkt_col,
                                                x, W_src, W_dst, W_fc, xb, wbf);
    k_prep<<<(NN * 32 + 255) / 256, 256, 0, stream>>>(cnt, (const float4*)x,
                                                      invb, w2, (uint2*)xs);

    float* o_inv = invb;
    float* i_inv = invb + NN;
    float* out_p  = (float*)d_out;
    float* cin_p  = out_p + (size_t)NN * DD;
    float* cout_p = cin_p + NN;

    k_gather<<<NN / 2, 256, 0, stream>>>((const uint4*)xs, (const float4*)x,
                                         bkt_row, bkt_col, cnt,
                                         o_inv, i_inv, w2, in_degree, out_degree,
                                         odm, odmb, idm, idmb,
                                         (const float4*)W_out_f, b_out_f,
                                         (const float4*)W_in_f, b_in_f,
                                         (const float4*)in_tab, (const float4*)out_tab,
                                         (uint2*)onb, (uint2*)inb,
                                         scbuf, cin_p, cout_p);

    k_gemm<<<(NN + MT - 1) / MT, 256, 0, stream>>>(
        (const unsigned int*)xb, (const unsigned int*)onb, (const unsigned int*)inb,
        wbf, b_src, b_dst, b_fc, scbuf, out_p);
}